// Round 19
// baseline (451.792 us; speedup 1.0000x reference)
//
#include <hip/hip_runtime.h>
#include <stdint.h>
#include <stddef.h>

#define NN 8192
#define FD 512
#define ATTN_OFF (NN * FD)

typedef __attribute__((ext_vector_type(8))) short bf16x8;
typedef __attribute__((ext_vector_type(4))) float f32x4;
typedef __attribute__((ext_vector_type(4))) int i32x4;
typedef __attribute__((ext_vector_type(2))) uint32_t u32x2;
typedef __attribute__((ext_vector_type(4))) uint32_t u32x4;
typedef __attribute__((ext_vector_type(4))) uint16_t u16x4;

static __device__ __forceinline__ uint16_t f2bf(float x){
    union { float f; uint32_t u; } v; v.f = x;
    uint32_t r = v.u + 0x7FFFu + ((v.u >> 16) & 1u);
    return (uint16_t)(r >> 16);
}

#define GLDS(gp, lp) \
    __builtin_amdgcn_global_load_lds((__attribute__((address_space(1))) void*)(gp), \
                                     (__attribute__((address_space(3))) void*)(lp), 16, 0, 0)

// ---------------- u = W @ a1, v = W @ a2 --------------------------------------------
__global__ void k_va(const float* __restrict__ W, const float* __restrict__ a,
                     float* __restrict__ va1, float* __restrict__ va2){
    const int lane = threadIdx.x & 63, wave = threadIdx.x >> 6;
    const int k = blockIdx.x*8 + wave;
    const float* wr = W + (size_t)k*FD;
    float s1 = 0.f, s2 = 0.f;
    #pragma unroll
    for (int e = 0; e < 2; ++e){
        int c = e*256 + lane*4;
        f32x4 wv = *(const f32x4*)(wr + c);
        f32x4 x1 = *(const f32x4*)(a + c);
        f32x4 x2 = *(const f32x4*)(a + FD + c);
        s1 += wv[0]*x1[0] + wv[1]*x1[1] + wv[2]*x1[2] + wv[3]*x1[3];
        s2 += wv[0]*x2[0] + wv[1]*x2[1] + wv[2]*x2[2] + wv[3]*x2[3];
    }
    for (int off = 32; off; off >>= 1){ s1 += __shfl_down(s1, off); s2 += __shfl_down(s2, off); }
    if (lane == 0){ va1[k] = s1; va2[k] = s2; }
}

// ---------------- W -> bf16 transposed ----------------------------------------------
__global__ void k_convW(const float* __restrict__ W, uint16_t* __restrict__ WT_b){
    int idx = blockIdx.x * 256 + threadIdx.x;
    for (int i = idx; i < FD*FD; i += 256*256){
        int n = i >> 9, k = i & 511;
        WT_b[i] = f2bf(W[(size_t)k*FD + n]);
    }
}

// ---------------- per-row s1,s2, exp tables, h -> bf16 ------------------------------
__global__ void k_rows(const float* __restrict__ h, const float* __restrict__ va1,
                       const float* __restrict__ va2, uint16_t* __restrict__ h_b,
                       float* __restrict__ Tarr,
                       float* __restrict__ E1p, float* __restrict__ E1n,
                       float* __restrict__ E2p, float* __restrict__ E2n){
    const int lane = threadIdx.x & 63, wave = threadIdx.x >> 6;
    const int row = blockIdx.x*4 + wave;
    const float* hr = h + (size_t)row * FD;
    float s1 = 0.f, s2 = 0.f;
    #pragma unroll
    for (int e = 0; e < 2; ++e){
        int c = e*256 + lane*4;
        f32x4 hv = *(const f32x4*)(hr + c);
        f32x4 x1 = *(const f32x4*)(va1 + c);
        f32x4 x2 = *(const f32x4*)(va2 + c);
        s1 += hv[0]*x1[0] + hv[1]*x1[1] + hv[2]*x1[2] + hv[3]*x1[3];
        s2 += hv[0]*x2[0] + hv[1]*x2[1] + hv[2]*x2[2] + hv[3]*x2[3];
        u16x4 o;
        o[0]=f2bf(hv[0]); o[1]=f2bf(hv[1]); o[2]=f2bf(hv[2]); o[3]=f2bf(hv[3]);
        *(u16x4*)(h_b + (size_t)row*FD + c) = o;
    }
    for (int off = 32; off; off >>= 1){ s1 += __shfl_down(s1, off); s2 += __shfl_down(s2, off); }
    if (lane == 0){
        Tarr[row] = expf(-s1);        // threshold: x>0  <=>  E2p[j] > T[i]
        E1p[row]  = expf(s1);
        E1n[row]  = expf(0.2f*s1);
        E2p[row]  = expf(s2);
        E2n[row]  = expf(0.2f*s2);
    }
}

// ---------------- pass over adj: denominators + bit-pack (NO LDS: occupancy) --------
__global__ __launch_bounds__(256) void k_pack(
                       const int* __restrict__ adj, const float* __restrict__ Tarr,
                       const float* __restrict__ E1p, const float* __restrict__ E1n,
                       const float* __restrict__ E2p, const float* __restrict__ E2n,
                       uint32_t* __restrict__ packed, float* __restrict__ rowP,
                       float* __restrict__ rowN){
    const int tid = threadIdx.x, lane = tid & 63, wave = tid >> 6;
    const int row = blockIdx.x*4 + wave;
    const float T_i = Tarr[row];
    const int* arow = adj + (size_t)row * NN;
    float Ap = 0.f, An = 0.f;
    #pragma unroll
    for (int g = 0; g < 4; ++g){
        uint32_t word = 0;
        #pragma unroll
        for (int e = 0; e < 8; ++e){
            int j0 = g*2048 + e*256 + lane*4;
            i32x4 av = __builtin_nontemporal_load((const i32x4*)(arow + j0));
            f32x4 p = *(const f32x4*)(E2p + j0);
            f32x4 q = *(const f32x4*)(E2n + j0);
            #pragma unroll
            for (int c = 0; c < 4; ++c){
                if (av[c] != 0){
                    if (p[c] > T_i) Ap += p[c]; else An += q[c];
                    word |= (1u << (e*4 + c));
                }
            }
        }
        packed[(size_t)row*256 + g*64 + lane] = word;
    }
    #pragma unroll
    for (int off = 32; off; off >>= 1){
        Ap += __shfl_xor(Ap, off);
        An += __shfl_xor(An, off);
    }
    if (lane == 0){
        float e1p = E1p[row], e1n = E1n[row];
        float inv = 1.0f / (e1p*Ap + e1n*An);
        rowP[row] = e1p * inv;
        rowN[row] = e1n * inv;
    }
}

// ---------------- MFMA inner tile, M=32 (k_wh) --------------------------------------
static __device__ __forceinline__ void mfma_tile(const char* A_base, const char* B_base,
                                                 int wave, int lane, f32x4 acc[2][4]){
    #pragma unroll
    for (int kk = 0; kk < 2; ++kk){
        bf16x8 afr[2], bfr[4];
        #pragma unroll
        for (int t = 0; t < 2; ++t){
            int rowl = t*16 + (lane & 15);
            int slot = (kk*4 + (lane >> 4)) ^ (rowl & 7);
            afr[t] = *(const bf16x8*)(A_base + rowl*128 + slot*16);
        }
        #pragma unroll
        for (int n = 0; n < 4; ++n){
            int nl = wave*64 + n*16 + (lane & 15);
            int slot = (kk*4 + (lane >> 4)) ^ (nl & 7);
            bfr[n] = *(const bf16x8*)(B_base + nl*128 + slot*16);
        }
        #pragma unroll
        for (int t = 0; t < 2; ++t)
            #pragma unroll
            for (int n = 0; n < 4; ++n)
                acc[t][n] = __builtin_amdgcn_mfma_f32_16x16x32_bf16(afr[t], bfr[n], acc[t][n], 0, 0, 0);
    }
}

// ---------------- Wh GEMM: WhbT[n][m] = bf16( h[m,:] @ W[:,n] ) ---------------------
__global__ __launch_bounds__(512) void k_wh(const uint16_t* __restrict__ h_b,
                                            const uint16_t* __restrict__ WT_b,
                                            uint16_t* __restrict__ WhbT){
    extern __shared__ char smem[];
    char* A_base = smem;
    char* B_base = smem + 4096;
    const int tid = threadIdx.x, wave = tid >> 6, lane = tid & 63;
    const int mb0 = blockIdx.x * 32;
    f32x4 acc[2][4];
    #pragma unroll
    for (int t = 0; t < 2; ++t)
        #pragma unroll
        for (int n = 0; n < 4; ++n) acc[t][n] = (f32x4){0.f,0.f,0.f,0.f};

    for (int k0 = 0; k0 < FD; k0 += 64){
        if (wave < 4){
            int m = wave*8 + (lane >> 3);
            int chunk = (lane & 7) ^ (m & 7);
            GLDS(h_b + (size_t)(mb0 + m)*FD + k0 + chunk*8, A_base + wave*1024);
        }
        #pragma unroll
        for (int r = 0; r < 8; ++r){
            int nn = wave*64 + r*8 + (lane >> 3);
            int chunk = (lane & 7) ^ (nn & 7);
            GLDS(WT_b + (size_t)nn*FD + k0 + chunk*8, B_base + (wave*64 + r*8)*128);
        }
        __syncthreads();
        mfma_tile(A_base, B_base, wave, lane, acc);
        __syncthreads();
    }
    uint16_t* Ts = (uint16_t*)B_base;
    #pragma unroll
    for (int t = 0; t < 2; ++t)
        #pragma unroll
        for (int n = 0; n < 4; ++n)
            #pragma unroll
            for (int r = 0; r < 4; ++r){
                int nl = wave*64 + n*16 + (lane & 15);
                int m  = t*16 + (lane >> 4)*4 + r;
                Ts[nl*40 + m] = f2bf(acc[t][n][r]);
            }
    __syncthreads();
    {
        int n = tid;
        const u32x4* src = (const u32x4*)(Ts + n*40);
        u32x4* dst = (u32x4*)(WhbT + (size_t)n*NN + mb0);
        #pragma unroll
        for (int r = 0; r < 4; ++r) dst[r] = src[r];
    }
}

// ---------------- fused: M=64 tile, 2 blocks/CU, T14-split GEN ----------------------
// r17 schedule with halved M: acc[4][4]=64 AGPR + LDS 72KB -> 2 blocks/CU, so a
// co-resident block fills every barrier stall. grid 512 = 128 m-blocks x 4 k-splits.
__global__ __launch_bounds__(512, 4) void k_gemm(
                                              const uint32_t* __restrict__ packed,
                                              const uint16_t* __restrict__ WhbT,
                                              const float* __restrict__ Tarr,
                                              const float* __restrict__ rowP,
                                              const float* __restrict__ rowN,
                                              const float* __restrict__ E2p,
                                              const float* __restrict__ E2n,
                                              float* __restrict__ hp_part,
                                              float* __restrict__ out){
    extern __shared__ char smem[];
    char* A_lds = smem;             // 2 x 4KB  [64][32] bf16, 16B-slot XOR swizzle
    char* B_lds = smem + 8192;      // 2 x 32KB [512][32] bf16, same swizzle (72KB)

    const int tid = threadIdx.x, wave = tid >> 6, lane = tid & 63;
    const int il = tid >> 3, jg = tid & 7;       // il in [0,64): row; jg: 4-col group
    const int bi = blockIdx.x;
    const int ks = (bi & 7) >> 1;                 // 4 k-splits, XCD-pair pinned
    const int m_idx = (bi >> 3)*2 + (bi & 1);     // [0,128)
    const int row0 = m_idx * 64;
    const int kbase = ks * 2048;

    const int grow = row0 + il;
    const float Tv = Tarr[grow], rPv = rowP[grow], rNv = rowN[grow];
    float* obase = out + ATTN_OFF + (size_t)grow*NN + kbase + jg*4;

    f32x4 acc[4][4];
    #pragma unroll
    for (int mi = 0; mi < 4; ++mi)
        #pragma unroll
        for (int n = 0; n < 4; ++n) acc[mi][n] = (f32x4){0.f,0.f,0.f,0.f};

    auto BLOAD = [&](int t, u32x4 br[4]){
        const int k0 = kbase + t*32;
        #pragma unroll
        for (int rr = 0; rr < 4; ++rr){
            int n  = wave*64 + rr*16 + (lane >> 2);
            int cg = lane & 3;
            br[rr] = *(const u32x4*)(WhbT + (size_t)n*NN + k0 + cg*8);
        }
    };
    auto GEN_LOAD = [&](int t, f32x4& p, f32x4& q, uint32_t& wv){
        const int k0 = kbase + t*32;
        p = *(const f32x4*)(E2p + k0 + jg*4);
        q = *(const f32x4*)(E2n + k0 + jg*4);
        wv = packed[(size_t)grow*256 + ks*64 + (t & 7)*8 + jg];
    };
    auto GEN_STORE = [&](int t, const f32x4& p, const f32x4& q, uint32_t wv,
                         uint32_t aw[2]){
        const int shift = ((t >> 3) & 7)*4;
        float va[4];
        #pragma unroll
        for (int c = 0; c < 4; ++c){
            float val = (p[c] > Tv) ? rPv*p[c] : rNv*q[c];
            va[c] = ((wv >> (shift + c)) & 1u) ? val : 0.f;
        }
        f32x4 st; st[0]=va[0]; st[1]=va[1]; st[2]=va[2]; st[3]=va[3];
        __builtin_nontemporal_store(st, (f32x4*)(obase + t*32));
        aw[0] = ((uint32_t)f2bf(va[1]) << 16) | f2bf(va[0]);
        aw[1] = ((uint32_t)f2bf(va[3]) << 16) | f2bf(va[2]);
    };
    auto WRITE_LDS = [&](int side, uint32_t aw[2], u32x4 br[4]){
        char* A = A_lds + side*4096;
        char* B = B_lds + side*32768;
        {
            int addr = il*64 + (((jg >> 1) ^ (il & 3)) << 4) + ((jg & 1) << 3);
            u32x2 w; w[0] = aw[0]; w[1] = aw[1];
            *(u32x2*)(A + addr) = w;
        }
        #pragma unroll
        for (int rr = 0; rr < 4; ++rr){
            int n  = wave*64 + rr*16 + (lane >> 2);
            int cg = lane & 3;
            *(u32x4*)(B + n*64 + ((cg ^ (n & 3)) << 4)) = br[rr];
        }
    };

    {   // prologue: step 0 into side 0
        uint32_t aw[2]; u32x4 br[4]; f32x4 p, q; uint32_t wv;
        BLOAD(0, br); GEN_LOAD(0, p, q, wv);
        GEN_STORE(0, p, q, wv, aw);
        WRITE_LDS(0, aw, br);
        asm volatile("s_waitcnt lgkmcnt(0)" ::: "memory");
        __builtin_amdgcn_s_barrier();
    }

    for (int t = 0; t < 64; ++t){
        uint32_t aw[2]; u32x4 br[4]; f32x4 p, q; uint32_t wv;
        if (t < 63){ BLOAD(t+1, br); GEN_LOAD(t+1, p, q, wv); }
        {   // MFMA on side t&1 — covers the load latency above
            const char* A = A_lds + (t & 1)*4096;
            const char* B = B_lds + (t & 1)*32768;
            bf16x8 afr[4], bfr[4];
            #pragma unroll
            for (int mi = 0; mi < 4; ++mi){
                int rowl = mi*16 + (lane & 15);
                afr[mi] = *(const bf16x8*)(A + rowl*64 + (((lane >> 4) ^ (rowl & 3)) << 4));
            }
            #pragma unroll
            for (int nf = 0; nf < 4; ++nf){
                int nl = wave*64 + nf*16 + (lane & 15);
                bfr[nf] = *(const bf16x8*)(B + nl*64 + (((lane >> 4) ^ (nl & 3)) << 4));
            }
            __builtin_amdgcn_s_setprio(1);
            #pragma unroll
            for (int mi = 0; mi < 4; ++mi)
                #pragma unroll
                for (int nf = 0; nf < 4; ++nf)
                    acc[mi][nf] = __builtin_amdgcn_mfma_f32_16x16x32_bf16(afr[mi], bfr[nf], acc[mi][nf], 0, 0, 0);
            __builtin_amdgcn_s_setprio(0);
        }
        if (t < 63){
            GEN_STORE(t+1, p, q, wv, aw);   // consume loads AFTER MFMA
            WRITE_LDS((t+1) & 1, aw, br);   // br wait never drains the younger stores
            asm volatile("s_waitcnt lgkmcnt(0)" ::: "memory");
            __builtin_amdgcn_s_barrier();
        }
    }
    // epilogue: f32 partial
    float* hp = hp_part + (size_t)ks * NN * FD;
    #pragma unroll
    for (int mi = 0; mi < 4; ++mi)
        #pragma unroll
        for (int n = 0; n < 4; ++n)
            #pragma unroll
            for (int r = 0; r < 4; ++r){
                int m   = row0 + mi*16 + (lane >> 4)*4 + r;
                int col = wave*64 + n*16 + (lane & 15);
                hp[(size_t)m*FD + col] = acc[mi][n][r];
            }
}

// ---------------- reduce 4 k-split partials + ELU -----------------------------------
__global__ __launch_bounds__(512) void k_red(const float* __restrict__ hp,
                                             float* __restrict__ out){
    const size_t i = (size_t)blockIdx.x * 512 + threadIdx.x;
    const size_t off = (size_t)NN * FD / 4;
    f32x4 a = ((const f32x4*)hp)[i];
    f32x4 b = ((const f32x4*)hp)[i + off];
    f32x4 c = ((const f32x4*)hp)[i + off*2];
    f32x4 d = ((const f32x4*)hp)[i + off*3];
    f32x4 s;
    #pragma unroll
    for (int e = 0; e < 4; ++e){
        float x = (a[e] + b[e]) + (c[e] + d[e]);
        s[e] = (x > 0.f) ? x : expm1f(x);
    }
    ((f32x4*)out)[i] = s;
}

extern "C" void kernel_launch(void* const* d_in, const int* in_sizes, int n_in,
                              void* d_out, int out_size, void* d_ws, size_t ws_size,
                              hipStream_t stream){
    (void)in_sizes; (void)n_in; (void)out_size; (void)ws_size;
    const float* h   = (const float*)d_in[0];
    const int*   adj = (const int*)  d_in[1];
    const float* W   = (const float*)d_in[2];
    const float* a   = (const float*)d_in[3];
    float* out = (float*)d_out;

    char* ws = (char*)d_ws;
    uint16_t* WhbT   = (uint16_t*)(ws);                      // 8MB  [512][8192] bf16
    uint16_t* h_b    = (uint16_t*)(ws + (8u<<20));           // 8MB (dead after k_wh)
    uint32_t* packed = (uint32_t*)(ws + (8u<<20));           // 8MB, aliases h_b
    uint16_t* WT_b   = (uint16_t*)(ws + (16u<<20));          // 512KB
    float* fb   = (float*)(ws + (17u<<20));                  // small arrays
    float* va1  = fb;            float* va2  = fb + 512;
    float* Tarr = fb + 1024;
    float* E1p  = Tarr + NN;     float* E1n  = E1p + NN;
    float* E2p  = E1n + NN;      float* E2n  = E2p + NN;
    float* rowP = E2n + NN;      float* rowN = rowP + NN;
    float* hp_part = (float*)(ws + (32u<<20));               // 64MB: 4 x [8192][512] f32

    hipFuncSetAttribute((const void*)k_wh,   hipFuncAttributeMaxDynamicSharedMemorySize, 69632);
    hipFuncSetAttribute((const void*)k_gemm, hipFuncAttributeMaxDynamicSharedMemorySize, 73728);

    k_va   <<<64,   512, 0,      stream>>>(W, a, va1, va2);
    k_rows <<<2048, 256, 0,      stream>>>(h, va1, va2, h_b, Tarr, E1p, E1n, E2p, E2n);
    k_convW<<<256,  256, 0,      stream>>>(W, WT_b);
    k_wh   <<<256,  512, 69632,  stream>>>(h_b, WT_b, WhbT);   // h_b dead after this
    k_pack <<<2048, 256, 0,      stream>>>(adj, Tarr, E1p, E1n, E2p, E2n, packed, rowP, rowN);
    k_gemm <<<512,  512, 73728,  stream>>>(packed, WhbT, Tarr, rowP, rowN, E2p, E2n, hp_part, out);
    k_red  <<<2048, 512, 0,      stream>>>(hp_part, out);
}

// Round 20
// 200.781 us; speedup vs baseline: 2.2502x; 2.2502x over previous
//
#include <hip/hip_runtime.h>
#include <stdint.h>
#include <stddef.h>

#define NN 8192
#define FD 512
#define ATTN_OFF (NN * FD)

typedef __attribute__((ext_vector_type(8))) short bf16x8;
typedef __attribute__((ext_vector_type(4))) float f32x4;
typedef __attribute__((ext_vector_type(4))) int i32x4;
typedef __attribute__((ext_vector_type(2))) uint32_t u32x2;
typedef __attribute__((ext_vector_type(4))) uint32_t u32x4;
typedef __attribute__((ext_vector_type(4))) uint16_t u16x4;

static __device__ __forceinline__ uint16_t f2bf(float x){
    union { float f; uint32_t u; } v; v.f = x;
    uint32_t r = v.u + 0x7FFFu + ((v.u >> 16) & 1u);
    return (uint16_t)(r >> 16);
}

#define GLDS(gp, lp) \
    __builtin_amdgcn_global_load_lds((__attribute__((address_space(1))) void*)(gp), \
                                     (__attribute__((address_space(3))) void*)(lp), 16, 0, 0)

// ---------------- u = W @ a1, v = W @ a2 --------------------------------------------
__global__ void k_va(const float* __restrict__ W, const float* __restrict__ a,
                     float* __restrict__ va1, float* __restrict__ va2){
    const int lane = threadIdx.x & 63, wave = threadIdx.x >> 6;
    const int k = blockIdx.x*8 + wave;
    const float* wr = W + (size_t)k*FD;
    float s1 = 0.f, s2 = 0.f;
    #pragma unroll
    for (int e = 0; e < 2; ++e){
        int c = e*256 + lane*4;
        f32x4 wv = *(const f32x4*)(wr + c);
        f32x4 x1 = *(const f32x4*)(a + c);
        f32x4 x2 = *(const f32x4*)(a + FD + c);
        s1 += wv[0]*x1[0] + wv[1]*x1[1] + wv[2]*x1[2] + wv[3]*x1[3];
        s2 += wv[0]*x2[0] + wv[1]*x2[1] + wv[2]*x2[2] + wv[3]*x2[3];
    }
    for (int off = 32; off; off >>= 1){ s1 += __shfl_down(s1, off); s2 += __shfl_down(s2, off); }
    if (lane == 0){ va1[k] = s1; va2[k] = s2; }
}

// ---------------- W -> bf16 transposed ----------------------------------------------
__global__ void k_convW(const float* __restrict__ W, uint16_t* __restrict__ WT_b){
    int idx = blockIdx.x * 256 + threadIdx.x;
    for (int i = idx; i < FD*FD; i += 256*256){
        int n = i >> 9, k = i & 511;
        WT_b[i] = f2bf(W[(size_t)k*FD + n]);
    }
}

// ---------------- per-row s1,s2, exp tables, h -> bf16 ------------------------------
__global__ void k_rows(const float* __restrict__ h, const float* __restrict__ va1,
                       const float* __restrict__ va2, uint16_t* __restrict__ h_b,
                       float* __restrict__ Tarr,
                       float* __restrict__ E1p, float* __restrict__ E1n,
                       float* __restrict__ E2p, float* __restrict__ E2n){
    const int lane = threadIdx.x & 63, wave = threadIdx.x >> 6;
    const int row = blockIdx.x*4 + wave;
    const float* hr = h + (size_t)row * FD;
    float s1 = 0.f, s2 = 0.f;
    #pragma unroll
    for (int e = 0; e < 2; ++e){
        int c = e*256 + lane*4;
        f32x4 hv = *(const f32x4*)(hr + c);
        f32x4 x1 = *(const f32x4*)(va1 + c);
        f32x4 x2 = *(const f32x4*)(va2 + c);
        s1 += hv[0]*x1[0] + hv[1]*x1[1] + hv[2]*x1[2] + hv[3]*x1[3];
        s2 += hv[0]*x2[0] + hv[1]*x2[1] + hv[2]*x2[2] + hv[3]*x2[3];
        u16x4 o;
        o[0]=f2bf(hv[0]); o[1]=f2bf(hv[1]); o[2]=f2bf(hv[2]); o[3]=f2bf(hv[3]);
        *(u16x4*)(h_b + (size_t)row*FD + c) = o;
    }
    for (int off = 32; off; off >>= 1){ s1 += __shfl_down(s1, off); s2 += __shfl_down(s2, off); }
    if (lane == 0){
        Tarr[row] = expf(-s1);        // threshold: x>0  <=>  E2p[j] > T[i]
        E1p[row]  = expf(s1);
        E1n[row]  = expf(0.2f*s1);
        E2p[row]  = expf(s2);
        E2n[row]  = expf(0.2f*s2);
    }
}

// ---------------- pass over adj: denominators + bit-pack (NO LDS: occupancy) --------
__global__ __launch_bounds__(256) void k_pack(
                       const int* __restrict__ adj, const float* __restrict__ Tarr,
                       const float* __restrict__ E1p, const float* __restrict__ E1n,
                       const float* __restrict__ E2p, const float* __restrict__ E2n,
                       uint32_t* __restrict__ packed, float* __restrict__ rowP,
                       float* __restrict__ rowN){
    const int tid = threadIdx.x, lane = tid & 63, wave = tid >> 6;
    const int row = blockIdx.x*4 + wave;
    const float T_i = Tarr[row];
    const int* arow = adj + (size_t)row * NN;
    float Ap = 0.f, An = 0.f;
    #pragma unroll
    for (int g = 0; g < 4; ++g){
        uint32_t word = 0;
        #pragma unroll
        for (int e = 0; e < 8; ++e){
            int j0 = g*2048 + e*256 + lane*4;
            i32x4 av = __builtin_nontemporal_load((const i32x4*)(arow + j0));
            f32x4 p = *(const f32x4*)(E2p + j0);
            f32x4 q = *(const f32x4*)(E2n + j0);
            #pragma unroll
            for (int c = 0; c < 4; ++c){
                if (av[c] != 0){
                    if (p[c] > T_i) Ap += p[c]; else An += q[c];
                    word |= (1u << (e*4 + c));
                }
            }
        }
        packed[(size_t)row*256 + g*64 + lane] = word;
    }
    #pragma unroll
    for (int off = 32; off; off >>= 1){
        Ap += __shfl_xor(Ap, off);
        An += __shfl_xor(An, off);
    }
    if (lane == 0){
        float e1p = E1p[row], e1n = E1n[row];
        float inv = 1.0f / (e1p*Ap + e1n*An);
        rowP[row] = e1p * inv;
        rowN[row] = e1n * inv;
    }
}

// ---------------- MFMA inner tile, M=32 (k_wh) --------------------------------------
static __device__ __forceinline__ void mfma_tile(const char* A_base, const char* B_base,
                                                 int wave, int lane, f32x4 acc[2][4]){
    #pragma unroll
    for (int kk = 0; kk < 2; ++kk){
        bf16x8 afr[2], bfr[4];
        #pragma unroll
        for (int t = 0; t < 2; ++t){
            int rowl = t*16 + (lane & 15);
            int slot = (kk*4 + (lane >> 4)) ^ (rowl & 7);
            afr[t] = *(const bf16x8*)(A_base + rowl*128 + slot*16);
        }
        #pragma unroll
        for (int n = 0; n < 4; ++n){
            int nl = wave*64 + n*16 + (lane & 15);
            int slot = (kk*4 + (lane >> 4)) ^ (nl & 7);
            bfr[n] = *(const bf16x8*)(B_base + nl*128 + slot*16);
        }
        #pragma unroll
        for (int t = 0; t < 2; ++t)
            #pragma unroll
            for (int n = 0; n < 4; ++n)
                acc[t][n] = __builtin_amdgcn_mfma_f32_16x16x32_bf16(afr[t], bfr[n], acc[t][n], 0, 0, 0);
    }
}

// ---------------- Wh GEMM: WhbT[n][m] = bf16( h[m,:] @ W[:,n] ) ---------------------
__global__ __launch_bounds__(512) void k_wh(const uint16_t* __restrict__ h_b,
                                            const uint16_t* __restrict__ WT_b,
                                            uint16_t* __restrict__ WhbT){
    extern __shared__ char smem[];
    char* A_base = smem;
    char* B_base = smem + 4096;
    const int tid = threadIdx.x, wave = tid >> 6, lane = tid & 63;
    const int mb0 = blockIdx.x * 32;
    f32x4 acc[2][4];
    #pragma unroll
    for (int t = 0; t < 2; ++t)
        #pragma unroll
        for (int n = 0; n < 4; ++n) acc[t][n] = (f32x4){0.f,0.f,0.f,0.f};

    for (int k0 = 0; k0 < FD; k0 += 64){
        if (wave < 4){
            int m = wave*8 + (lane >> 3);
            int chunk = (lane & 7) ^ (m & 7);
            GLDS(h_b + (size_t)(mb0 + m)*FD + k0 + chunk*8, A_base + wave*1024);
        }
        #pragma unroll
        for (int r = 0; r < 8; ++r){
            int nn = wave*64 + r*8 + (lane >> 3);
            int chunk = (lane & 7) ^ (nn & 7);
            GLDS(WT_b + (size_t)nn*FD + k0 + chunk*8, B_base + (wave*64 + r*8)*128);
        }
        __syncthreads();
        mfma_tile(A_base, B_base, wave, lane, acc);
        __syncthreads();
    }
    uint16_t* Ts = (uint16_t*)B_base;
    #pragma unroll
    for (int t = 0; t < 2; ++t)
        #pragma unroll
        for (int n = 0; n < 4; ++n)
            #pragma unroll
            for (int r = 0; r < 4; ++r){
                int nl = wave*64 + n*16 + (lane & 15);
                int m  = t*16 + (lane >> 4)*4 + r;
                Ts[nl*40 + m] = f2bf(acc[t][n][r]);
            }
    __syncthreads();
    {
        int n = tid;
        const u32x4* src = (const u32x4*)(Ts + n*40);
        u32x4* dst = (u32x4*)(WhbT + (size_t)n*NN + mb0);
        #pragma unroll
        for (int r = 0; r < 4; ++r) dst[r] = src[r];
    }
}

// ---------------- fused: GEN split (T14) + attn f32 store + GEMM --------------------
// Best measured config (r17): M=128, 1 block/CU keeps the B panel L2-resident;
// GEN_LOAD before MFMA / GEN_STORE after hides the p/q/packed L2 latency.
__global__ __launch_bounds__(512) void k_gemm(const uint32_t* __restrict__ packed,
                                              const uint16_t* __restrict__ WhbT,
                                              const float* __restrict__ Tarr,
                                              const float* __restrict__ rowP,
                                              const float* __restrict__ rowN,
                                              const float* __restrict__ E2p,
                                              const float* __restrict__ E2n,
                                              float* __restrict__ hp_part,
                                              float* __restrict__ out){
    extern __shared__ char smem[];
    char* A_lds = smem;             // 2 x 8KB  [128][32] bf16, 16B-slot XOR swizzle
    char* B_lds = smem + 16384;     // 2 x 32KB [512][32] bf16, same swizzle (80KB)

    const int tid = threadIdx.x, wave = tid >> 6, lane = tid & 63;
    const int il = tid >> 3, jg = tid & 7;
    const int bi = blockIdx.x;
    const int ks = (bi & 7) >> 1;
    const int m_idx = (bi >> 3)*2 + (bi & 1);
    const int row0 = m_idx * 128;
    const int kbase = ks * 2048;

    float Tv[2], rPv[2], rNv[2];
    #pragma unroll
    for (int s = 0; s < 2; ++s){
        int gr = row0 + il + 64*s;
        Tv[s] = Tarr[gr]; rPv[s] = rowP[gr]; rNv[s] = rowN[gr];
    }

    f32x4 acc[8][4];
    #pragma unroll
    for (int mi = 0; mi < 8; ++mi)
        #pragma unroll
        for (int n = 0; n < 4; ++n) acc[mi][n] = (f32x4){0.f,0.f,0.f,0.f};

    auto BLOAD = [&](int t, u32x4 br[4]){
        const int k0 = kbase + t*32;
        #pragma unroll
        for (int rr = 0; rr < 4; ++rr){
            int n  = wave*64 + rr*16 + (lane >> 2);
            int cg = lane & 3;
            br[rr] = *(const u32x4*)(WhbT + (size_t)n*NN + k0 + cg*8);
        }
    };
    // T14 split: issue the GEN loads into registers; consumed only after MFMA.
    auto GEN_LOAD = [&](int t, f32x4& p, f32x4& q, uint32_t wv[2]){
        const int k0 = kbase + t*32;
        p = *(const f32x4*)(E2p + k0 + jg*4);
        q = *(const f32x4*)(E2n + k0 + jg*4);
        const int widx = ks*64 + (t & 7)*8 + jg;
        wv[0] = packed[(size_t)(row0 + il     )*256 + widx];
        wv[1] = packed[(size_t)(row0 + il + 64)*256 + widx];
    };
    auto GEN_STORE = [&](int t, const f32x4& p, const f32x4& q, const uint32_t wv[2],
                         uint32_t aw[2][2]){
        const int k0 = kbase + t*32;
        const int shift = ((t >> 3) & 7)*4;
        #pragma unroll
        for (int s = 0; s < 2; ++s){
            int grow = row0 + il + 64*s;
            float va[4];
            #pragma unroll
            for (int c = 0; c < 4; ++c){
                float val = (p[c] > Tv[s]) ? rPv[s]*p[c] : rNv[s]*q[c];
                va[c] = ((wv[s] >> (shift + c)) & 1u) ? val : 0.f;
            }
            f32x4 st; st[0]=va[0]; st[1]=va[1]; st[2]=va[2]; st[3]=va[3];
            __builtin_nontemporal_store(st, (f32x4*)(out + ATTN_OFF + (size_t)grow*NN + k0 + jg*4));
            aw[s][0] = ((uint32_t)f2bf(va[1]) << 16) | f2bf(va[0]);
            aw[s][1] = ((uint32_t)f2bf(va[3]) << 16) | f2bf(va[2]);
        }
    };
    auto WRITE_LDS = [&](int side, uint32_t aw[2][2], u32x4 br[4]){
        char* A = A_lds + side*8192;
        char* B = B_lds + side*32768;
        #pragma unroll
        for (int s = 0; s < 2; ++s){
            int rowl = il + 64*s;
            int addr = rowl*64 + (((jg >> 1) ^ (rowl & 3)) << 4) + ((jg & 1) << 3);
            u32x2 w; w[0] = aw[s][0]; w[1] = aw[s][1];
            *(u32x2*)(A + addr) = w;
        }
        #pragma unroll
        for (int rr = 0; rr < 4; ++rr){
            int n  = wave*64 + rr*16 + (lane >> 2);
            int cg = lane & 3;
            *(u32x4*)(B + n*64 + ((cg ^ (n & 3)) << 4)) = br[rr];
        }
    };

    {   // prologue: step 0 into side 0
        uint32_t aw[2][2]; u32x4 br[4]; f32x4 p, q; uint32_t wv[2];
        BLOAD(0, br); GEN_LOAD(0, p, q, wv);
        GEN_STORE(0, p, q, wv, aw);
        WRITE_LDS(0, aw, br);
        asm volatile("s_waitcnt lgkmcnt(0)" ::: "memory");
        __builtin_amdgcn_s_barrier();
    }

    for (int t = 0; t < 64; ++t){
        uint32_t aw[2][2]; u32x4 br[4]; f32x4 p, q; uint32_t wv[2];
        if (t < 63){ BLOAD(t+1, br); GEN_LOAD(t+1, p, q, wv); }
        {   // MFMA on side t&1 — covers the latency of the loads above
            const char* A = A_lds + (t & 1)*8192;
            const char* B = B_lds + (t & 1)*32768;
            bf16x8 afr[8], bfr[4];
            #pragma unroll
            for (int mi = 0; mi < 8; ++mi){
                int rowl = mi*16 + (lane & 15);
                afr[mi] = *(const bf16x8*)(A + rowl*64 + (((lane >> 4) ^ (rowl & 3)) << 4));
            }
            #pragma unroll
            for (int nf = 0; nf < 4; ++nf){
                int nl = wave*64 + nf*16 + (lane & 15);
                bfr[nf] = *(const bf16x8*)(B + nl*64 + (((lane >> 4) ^ (nl & 3)) << 4));
            }
            __builtin_amdgcn_s_setprio(1);
            #pragma unroll
            for (int mi = 0; mi < 8; ++mi)
                #pragma unroll
                for (int nf = 0; nf < 4; ++nf)
                    acc[mi][nf] = __builtin_amdgcn_mfma_f32_16x16x32_bf16(afr[mi], bfr[nf], acc[mi][nf], 0, 0, 0);
            __builtin_amdgcn_s_setprio(0);
        }
        if (t < 63){
            GEN_STORE(t+1, p, q, wv, aw);   // consume loads AFTER MFMA (latency hidden)
            WRITE_LDS((t+1) & 1, aw, br);   // br wait: stores issued after -> not drained
            asm volatile("s_waitcnt lgkmcnt(0)" ::: "memory");
            __builtin_amdgcn_s_barrier();
        }
    }
    // epilogue: f32 partial
    float* hp = hp_part + (size_t)ks * NN * FD;
    #pragma unroll
    for (int mi = 0; mi < 8; ++mi)
        #pragma unroll
        for (int n = 0; n < 4; ++n)
            #pragma unroll
            for (int r = 0; r < 4; ++r){
                int m   = row0 + mi*16 + (lane >> 4)*4 + r;
                int col = wave*64 + n*16 + (lane & 15);
                hp[(size_t)m*FD + col] = acc[mi][n][r];
            }
}

// ---------------- reduce 4 k-split partials + ELU -----------------------------------
__global__ __launch_bounds__(512) void k_red(const float* __restrict__ hp,
                                             float* __restrict__ out){
    const size_t i = (size_t)blockIdx.x * 512 + threadIdx.x;
    const size_t off = (size_t)NN * FD / 4;
    f32x4 a = ((const f32x4*)hp)[i];
    f32x4 b = ((const f32x4*)hp)[i + off];
    f32x4 c = ((const f32x4*)hp)[i + off*2];
    f32x4 d = ((const f32x4*)hp)[i + off*3];
    f32x4 s;
    #pragma unroll
    for (int e = 0; e < 4; ++e){
        float x = (a[e] + b[e]) + (c[e] + d[e]);
        s[e] = (x > 0.f) ? x : expm1f(x);
    }
    ((f32x4*)out)[i] = s;
}

extern "C" void kernel_launch(void* const* d_in, const int* in_sizes, int n_in,
                              void* d_out, int out_size, void* d_ws, size_t ws_size,
                              hipStream_t stream){
    (void)in_sizes; (void)n_in; (void)out_size; (void)ws_size;
    const float* h   = (const float*)d_in[0];
    const int*   adj = (const int*)  d_in[1];
    const float* W   = (const float*)d_in[2];
    const float* a   = (const float*)d_in[3];
    float* out = (float*)d_out;

    char* ws = (char*)d_ws;
    uint16_t* WhbT   = (uint16_t*)(ws);                      // 8MB  [512][8192] bf16
    uint16_t* h_b    = (uint16_t*)(ws + (8u<<20));           // 8MB (dead after k_wh)
    uint32_t* packed = (uint32_t*)(ws + (8u<<20));           // 8MB, aliases h_b
    uint16_t* WT_b   = (uint16_t*)(ws + (16u<<20));          // 512KB
    float* fb   = (float*)(ws + (17u<<20));                  // small arrays
    float* va1  = fb;            float* va2  = fb + 512;
    float* Tarr = fb + 1024;
    float* E1p  = Tarr + NN;     float* E1n  = E1p + NN;
    float* E2p  = E1n + NN;      float* E2n  = E2p + NN;
    float* rowP = E2n + NN;      float* rowN = rowP + NN;
    float* hp_part = (float*)(ws + (32u<<20));               // 64MB: 4 x [8192][512] f32

    hipFuncSetAttribute((const void*)k_wh,   hipFuncAttributeMaxDynamicSharedMemorySize, 69632);
    hipFuncSetAttribute((const void*)k_gemm, hipFuncAttributeMaxDynamicSharedMemorySize, 81920);

    k_va   <<<64,   512, 0,      stream>>>(W, a, va1, va2);
    k_rows <<<2048, 256, 0,      stream>>>(h, va1, va2, h_b, Tarr, E1p, E1n, E2p, E2n);
    k_convW<<<256,  256, 0,      stream>>>(W, WT_b);
    k_wh   <<<256,  512, 69632,  stream>>>(h_b, WT_b, WhbT);   // h_b dead after this
    k_pack <<<2048, 256, 0,      stream>>>(adj, Tarr, E1p, E1n, E2p, E2n, packed, rowP, rowN);
    k_gemm <<<256,  512, 81920,  stream>>>(packed, WhbT, Tarr, rowP, rowN, E2p, E2n, hp_part, out);
    k_red  <<<2048, 512, 0,      stream>>>(hp_part, out);
}